// Round 3
// baseline (499.898 us; speedup 1.0000x reference)
//
#include <hip/hip_runtime.h>

#define SEQ   2048
#define BATCH 2
#define EMB   512
#define NH    8
#define HD    64
#define CAPR  320         // contiguous support-list capacity per row

typedef short bf16x8 __attribute__((ext_vector_type(8)));
typedef float f32x4  __attribute__((ext_vector_type(4)));
typedef unsigned short ushort_t;

static __device__ __forceinline__ ushort_t f2bf(float f) {
    unsigned u = __float_as_uint(f);
    unsigned r = (u + 0x7FFF + ((u >> 16) & 1)) >> 16;   // rne
    return (ushort_t)r;
}
static __device__ __forceinline__ float bf2f(ushort_t h) {
    return __uint_as_float((unsigned)h << 16);
}

// =====================================================================
// Convert: split f32 -> bf16 hi/lo for q,k,v inputs + both weight mats.
// grid-stride over float4 groups.
// =====================================================================
#define Q4   524288
#define K4   1048576
#define V4   1572864
#define IW4  1769472
#define TOT4 1835008
__global__ __launch_bounds__(256) void convert_split(
    const float* __restrict__ q, const float* __restrict__ k,
    const float* __restrict__ v, const float* __restrict__ ipw,
    const float* __restrict__ opw,
    ushort_t* __restrict__ xqh, ushort_t* __restrict__ xql,
    ushort_t* __restrict__ xkh, ushort_t* __restrict__ xkl,
    ushort_t* __restrict__ xvh, ushort_t* __restrict__ xvl,
    ushort_t* __restrict__ iwh, ushort_t* __restrict__ iwl,
    ushort_t* __restrict__ owh, ushort_t* __restrict__ owl)
{
    for (long f = (long)blockIdx.x * 256 + threadIdx.x; f < TOT4;
         f += (long)gridDim.x * 256) {
        const float* src; ushort_t *dh, *dl; long o;
        if      (f < Q4)  { src = q;   dh = xqh; dl = xql; o = f; }
        else if (f < K4)  { src = k;   dh = xkh; dl = xkl; o = f - Q4; }
        else if (f < V4)  { src = v;   dh = xvh; dl = xvl; o = f - K4; }
        else if (f < IW4) { src = ipw; dh = iwh; dl = iwl; o = f - V4; }
        else              { src = opw; dh = owh; dl = owl; o = f - IW4; }
        const float4 x = ((const float4*)src)[o];
        ushort4 hi, lo;
        hi.x = f2bf(x.x); lo.x = f2bf(x.x - bf2f(hi.x));
        hi.y = f2bf(x.y); lo.y = f2bf(x.y - bf2f(hi.y));
        hi.z = f2bf(x.z); lo.z = f2bf(x.z - bf2f(hi.z));
        hi.w = f2bf(x.w); lo.w = f2bf(x.w - bf2f(hi.w));
        ((ushort4*)dh)[o] = hi;
        ((ushort4*)dl)[o] = lo;
    }
}

// =====================================================================
// GEMM1 (MFMA, split-bf16): X(4096x512) @ ipw[z-rows]^T -> +bias -> LN
// per 64-chunk -> (q only)*D^-0.5 -> [bh][i][d], Q/K split bf16, V f32.
// grid (32, 8, 3) block 256 (4 waves). Wave: 32 rows x 64 cols.
// =====================================================================
__global__ __launch_bounds__(256, 4) void gemm_qkv_ln_mfma(
    const ushort_t* __restrict__ xqh, const ushort_t* __restrict__ xql,
    const ushort_t* __restrict__ xkh, const ushort_t* __restrict__ xkl,
    const ushort_t* __restrict__ xvh, const ushort_t* __restrict__ xvl,
    const ushort_t* __restrict__ iwh, const ushort_t* __restrict__ iwl,
    const float* __restrict__ ipb,
    ushort_t* __restrict__ qhi, ushort_t* __restrict__ qlo,
    ushort_t* __restrict__ khi, ushort_t* __restrict__ klo,
    float* __restrict__ vn)
{
    const int z = blockIdx.z;
    const ushort_t* Ah = (z == 0) ? xqh : (z == 1) ? xkh : xvh;
    const ushort_t* Al = (z == 0) ? xql : (z == 1) ? xkl : xvl;
    ushort_t* dh = (z == 0) ? qhi : khi;
    ushort_t* dl = (z == 0) ? qlo : klo;
    const float scale = (z == 0) ? 0.125f : 1.0f;

    const int t0  = blockIdx.x * 128;
    const int h   = blockIdx.y;
    const int og0 = z * EMB + h * 64;

    const int tid = threadIdx.x;
    const int w   = tid >> 6;
    const int l   = tid & 63;
    const int c   = l & 15;
    const int g   = l >> 4;

    f32x4 acc[2][4];
#pragma unroll
    for (int mf = 0; mf < 2; ++mf)
#pragma unroll
        for (int nf = 0; nf < 4; ++nf) acc[mf][nf] = (f32x4){0.f, 0.f, 0.f, 0.f};

    const int arow0 = t0 + w * 32 + c;
#pragma unroll
    for (int ks = 0; ks < 16; ++ks) {
        const int k0 = ks * 32 + g * 8;
        bf16x8 ah[2], al[2], bh[4], bl[4];
#pragma unroll
        for (int mf = 0; mf < 2; ++mf) {
            const size_t r = (size_t)(arow0 + mf * 16) * EMB + k0;
            ah[mf] = *(const bf16x8*)&Ah[r];
            al[mf] = *(const bf16x8*)&Al[r];
        }
#pragma unroll
        for (int nf = 0; nf < 4; ++nf) {
            const size_t r = (size_t)(og0 + nf * 16 + c) * EMB + k0;
            bh[nf] = *(const bf16x8*)&iwh[r];
            bl[nf] = *(const bf16x8*)&iwl[r];
        }
#pragma unroll
        for (int mf = 0; mf < 2; ++mf)
#pragma unroll
            for (int nf = 0; nf < 4; ++nf) {
                f32x4 t = acc[mf][nf];
                t = __builtin_amdgcn_mfma_f32_16x16x32_bf16(ah[mf], bh[nf], t, 0, 0, 0);
                t = __builtin_amdgcn_mfma_f32_16x16x32_bf16(al[mf], bh[nf], t, 0, 0, 0);
                t = __builtin_amdgcn_mfma_f32_16x16x32_bf16(ah[mf], bl[nf], t, 0, 0, 0);
                acc[mf][nf] = t;
            }
    }

    // bias (per column)
#pragma unroll
    for (int nf = 0; nf < 4; ++nf) {
        const float bj = ipb[og0 + nf * 16 + c];
#pragma unroll
        for (int mf = 0; mf < 2; ++mf)
#pragma unroll
            for (int j = 0; j < 4; ++j) acc[mf][nf][j] += bj;
    }

    // LayerNorm per token row (64 cols = 4 nf x 16 lanes-in-group)
#pragma unroll
    for (int mf = 0; mf < 2; ++mf) {
        float mu[4], rs[4];
#pragma unroll
        for (int j = 0; j < 4; ++j) {
            float s = acc[mf][0][j] + acc[mf][1][j] + acc[mf][2][j] + acc[mf][3][j];
#pragma unroll
            for (int d = 1; d <= 8; d <<= 1) s += __shfl_xor(s, d);
            mu[j] = s * (1.0f / 64.0f);
        }
#pragma unroll
        for (int j = 0; j < 4; ++j) {
            float t = 0.f;
#pragma unroll
            for (int nf = 0; nf < 4; ++nf) {
                const float dv = acc[mf][nf][j] - mu[j];
                t += dv * dv;
            }
#pragma unroll
            for (int d = 1; d <= 8; d <<= 1) t += __shfl_xor(t, d);
            rs[j] = rsqrtf(t * (1.0f / 64.0f) + 1e-5f) * scale;
        }
#pragma unroll
        for (int j = 0; j < 4; ++j) {
            const int tg = t0 + w * 32 + mf * 16 + g * 4 + j;
            const int ii = tg >> 1;
            const int b  = tg & 1;
            const size_t base = ((size_t)(b * NH + h) * SEQ + ii) * 64 + c;
#pragma unroll
            for (int nf = 0; nf < 4; ++nf) {
                const float val = (acc[mf][nf][j] - mu[j]) * rs[j];
                const size_t a = base + nf * 16;
                if (z == 2) {
                    vn[a] = val;
                } else {
                    const ushort_t hi = f2bf(val);
                    dh[a] = hi;
                    dl[a] = f2bf(val - bf2f(hi));
                }
            }
        }
    }
}

// =====================================================================
// Fused attention: MFMA QK^T (split bf16) -> Michelot sparsemax ->
// contiguous-list sparse PV -> write ao as split bf16.
// grid 2048 (1D, XCD-swizzled)  block 512 (8 waves).
// =====================================================================
__global__ __launch_bounds__(512, 4) void attn_sparsemax_mfma(
    const ushort_t* __restrict__ qhi, const ushort_t* __restrict__ qlo,
    const ushort_t* __restrict__ khi, const ushort_t* __restrict__ klo,
    const float* __restrict__ vn,
    ushort_t* __restrict__ aoh, ushort_t* __restrict__ aol)
{
    __shared__ float    plist[16][CAPR];
    __shared__ ushort_t jlist[16][CAPR];
    __shared__ int      lcnt[16][8];
    __shared__ float    wred[8][16];
    __shared__ float    wcnt[8][16];
    __shared__ float    O_lds[16][64];

    const int tid = threadIdx.x;
    const int w   = tid >> 6;
    const int l   = tid & 63;
    const int c   = l & 15;
    const int g   = l >> 4;

    // XCD swizzle: all blocks of a (b,h) pair on one XCD (wgid%8 round-robin)
    const int wgid = blockIdx.x;
    const int xcd  = wgid & 7;
    const int idx  = wgid >> 3;              // 0..255
    const int bh   = xcd + 8 * (idx & 1);    // {xcd, xcd+8}
    const int q0   = (idx >> 1) * 16;        // 0..2032

    const size_t bhoff = (size_t)bh * SEQ * 64;
    const ushort_t* qh = qhi + bhoff;
    const ushort_t* ql = qlo + bhoff;
    const ushort_t* kh = khi + bhoff;
    const ushort_t* kl = klo + bhoff;
    const float*    vb = vn  + bhoff;

    for (int f = tid; f < 16 * 64; f += 512) ((float*)O_lds)[f] = 0.f;

    // A fragments (Q rows q0..q0+15)
    const size_t qrow = (size_t)(q0 + c) * 64 + g * 8;
    const bf16x8 ah0 = *(const bf16x8*)&qh[qrow];
    const bf16x8 ah1 = *(const bf16x8*)&qh[qrow + 32];
    const bf16x8 al0 = *(const bf16x8*)&ql[qrow];
    const bf16x8 al1 = *(const bf16x8*)&ql[qrow + 32];

    f32x4 acc[16];
#pragma unroll
    for (int nf = 0; nf < 16; ++nf) acc[nf] = (f32x4){0.f, 0.f, 0.f, 0.f};

    const int n0base = w * 256;
#pragma unroll
    for (int nf = 0; nf < 16; ++nf) {
        const size_t krow = (size_t)(n0base + nf * 16 + c) * 64 + g * 8;
        f32x4 t = acc[nf];
        const bf16x8 bh0 = *(const bf16x8*)&kh[krow];
        t = __builtin_amdgcn_mfma_f32_16x16x32_bf16(ah0, bh0, t, 0, 0, 0);
        t = __builtin_amdgcn_mfma_f32_16x16x32_bf16(al0, bh0, t, 0, 0, 0);
        const bf16x8 bh1 = *(const bf16x8*)&kh[krow + 32];
        t = __builtin_amdgcn_mfma_f32_16x16x32_bf16(ah1, bh1, t, 0, 0, 0);
        t = __builtin_amdgcn_mfma_f32_16x16x32_bf16(al1, bh1, t, 0, 0, 0);
        const bf16x8 bl0 = *(const bf16x8*)&kl[krow];
        t = __builtin_amdgcn_mfma_f32_16x16x32_bf16(ah0, bl0, t, 0, 0, 0);
        const bf16x8 bl1 = *(const bf16x8*)&kl[krow + 32];
        t = __builtin_amdgcn_mfma_f32_16x16x32_bf16(ah1, bl1, t, 0, 0, 0);
        acc[nf] = t;
    }

    // row max
    float mj[4];
#pragma unroll
    for (int j = 0; j < 4; ++j) {
        float m = acc[0][j];
#pragma unroll
        for (int nf = 1; nf < 16; ++nf) m = fmaxf(m, acc[nf][j]);
#pragma unroll
        for (int d = 1; d <= 8; d <<= 1) m = fmaxf(m, __shfl_xor(m, d));
        mj[j] = m;
    }
    if (c == 0) {
#pragma unroll
        for (int j = 0; j < 4; ++j) wred[w][g * 4 + j] = mj[j];
    }
    __syncthreads();

    float tau[4];
    int   cprev[4];
#pragma unroll
    for (int j = 0; j < 4; ++j) {
        float m = wred[0][g * 4 + j];
#pragma unroll
        for (int ww = 1; ww < 8; ++ww) m = fmaxf(m, wred[ww][g * 4 + j]);
        tau[j]   = m - 1.0f;
        cprev[j] = -1;
    }

    // Michelot fixed point
    for (int it = 0; it < 32; ++it) {
        __syncthreads();
        float sj[4], cj[4];
#pragma unroll
        for (int j = 0; j < 4; ++j) {
            float s = 0.f, cn = 0.f;
#pragma unroll
            for (int nf = 0; nf < 16; ++nf) {
                const float v = acc[nf][j];
                if (v > tau[j]) { s += v; cn += 1.f; }
            }
#pragma unroll
            for (int d = 1; d <= 8; d <<= 1) {
                s  += __shfl_xor(s, d);
                cn += __shfl_xor(cn, d);
            }
            sj[j] = s; cj[j] = cn;
        }
        if (c == 0) {
#pragma unroll
            for (int j = 0; j < 4; ++j) {
                wred[w][g * 4 + j] = sj[j];
                wcnt[w][g * 4 + j] = cj[j];
            }
        }
        __syncthreads();
        int changed = 0;
#pragma unroll
        for (int j = 0; j < 4; ++j) {
            float S = 0.f, C = 0.f;
#pragma unroll
            for (int ww = 0; ww < 8; ++ww) {
                S += wred[ww][g * 4 + j];
                C += wcnt[ww][g * 4 + j];
            }
            tau[j] = (S - 1.0f) / C;
            const int Ci = (int)C;
            changed |= (Ci != cprev[j]);
            cprev[j] = Ci;
        }
        if (!__any(changed)) break;
    }

    // ---- pass A: per-(row, wave) support counts ----
    int cnt[4] = {0, 0, 0, 0};
#pragma unroll
    for (int nf = 0; nf < 16; ++nf) {
#pragma unroll
        for (int j = 0; j < 4; ++j) {
            const bool on = (acc[nf][j] - tau[j]) > 0.f;
            const unsigned long long mask = __ballot(on);
            cnt[j] += __popc((unsigned)((mask >> (g * 16)) & 0xFFFFull));
        }
    }
    if (c == 0) {
#pragma unroll
        for (int j = 0; j < 4; ++j) lcnt[g * 4 + j][w] = cnt[j];
    }
    __syncthreads();

    // ---- pass B: write entries at cross-wave scanned positions ----
    int base[4];
#pragma unroll
    for (int j = 0; j < 4; ++j) {
        const int r = g * 4 + j;
        int b = 0;
        for (int ww = 0; ww < w; ++ww) b += lcnt[r][ww];
        base[j] = b;
    }
    int run[4] = {0, 0, 0, 0};
#pragma unroll
    for (int nf = 0; nf < 16; ++nf) {
#pragma unroll
        for (int j = 0; j < 4; ++j) {
            const float p  = acc[nf][j] - tau[j];
            const bool  on = p > 0.f;
            const unsigned long long mask = __ballot(on);
            const unsigned sub = (unsigned)((mask >> (g * 16)) & 0xFFFFull);
            if (on) {
                const int pos = base[j] + run[j] + __popc(sub & ((1u << c) - 1u));
                const int r   = g * 4 + j;
                const int col = n0base + nf * 16 + c;
                if (pos < CAPR) {
                    jlist[r][pos] = (ushort_t)col;
                    plist[r][pos] = p;
                } else {
                    for (int d = 0; d < 64; ++d)
                        atomicAdd(&O_lds[r][d], p * vb[(size_t)col * 64 + d]);
                }
            }
            run[j] += __popc(sub);
        }
    }
    __syncthreads();

    // ---- sparse PV, contiguous list, 4-way ILP ----
    const int bq = bh >> 3, hc = bh & 7;
#pragma unroll
    for (int rr = 0; rr < 2; ++rr) {
        const int r = w * 2 + rr;
        int n = 0;
#pragma unroll
        for (int ww = 0; ww < 8; ++ww) n += lcnt[r][ww];
        n = min(n, CAPR);
        float a0 = 0.f, a1 = 0.f, a2 = 0.f, a3 = 0.f;
        int e = 0;
        for (; e + 4 <= n; e += 4) {
            const int   j0 = jlist[r][e + 0], j1 = jlist[r][e + 1];
            const int   j2 = jlist[r][e + 2], j3 = jlist[r][e + 3];
            const float p0 = plist[r][e + 0], p1 = plist[r][e + 1];
            const float p2 = plist[r][e + 2], p3 = plist[r][e + 3];
            a0 += p0 * vb[(size_t)j0 * 64 + l];
            a1 += p1 * vb[(size_t)j1 * 64 + l];
            a2 += p2 * vb[(size_t)j2 * 64 + l];
            a3 += p3 * vb[(size_t)j3 * 64 + l];
        }
        for (; e < n; ++e)
            a0 += plist[r][e] * vb[(size_t)jlist[r][e] * 64 + l];
        const float val = a0 + a1 + a2 + a3 + O_lds[r][l];
        const int i = q0 + r;
        const size_t oa = (size_t)(i * BATCH + bq) * EMB + hc * 64 + l;
        const ushort_t hi = f2bf(val);
        aoh[oa] = hi;
        aol[oa] = f2bf(val - bf2f(hi));
    }
}

// =====================================================================
// GEMM2 (MFMA, split-bf16): ao(4096x512) @ opw^T + opb -> d_out (f32)
// grid (32, 8) block 256 (4 waves).
// =====================================================================
__global__ __launch_bounds__(256, 4) void gemm_out_mfma(
    const ushort_t* __restrict__ aoh, const ushort_t* __restrict__ aol,
    const ushort_t* __restrict__ owh, const ushort_t* __restrict__ owl,
    const float* __restrict__ opb, float* __restrict__ out)
{
    const int t0 = blockIdx.x * 128;
    const int o0 = blockIdx.y * 64;

    const int tid = threadIdx.x;
    const int w   = tid >> 6;
    const int l   = tid & 63;
    const int c   = l & 15;
    const int g   = l >> 4;

    f32x4 acc[2][4];
#pragma unroll
    for (int mf = 0; mf < 2; ++mf)
#pragma unroll
        for (int nf = 0; nf < 4; ++nf) acc[mf][nf] = (f32x4){0.f, 0.f, 0.f, 0.f};

    const int arow0 = t0 + w * 32 + c;
#pragma unroll
    for (int ks = 0; ks < 16; ++ks) {
        const int k0 = ks * 32 + g * 8;
        bf16x8 ah[2], al[2], bh[4], bl[4];
#pragma unroll
        for (int mf = 0; mf < 2; ++mf) {
            const size_t r = (size_t)(arow0 + mf * 16) * EMB + k0;
            ah[mf] = *(const bf16x8*)&aoh[r];
            al[mf] = *(const bf16x8*)&aol[r];
        }
#pragma unroll
        for (int nf = 0; nf < 4; ++nf) {
            const size_t r = (size_t)(o0 + nf * 16 + c) * EMB + k0;
            bh[nf] = *(const bf16x8*)&owh[r];
            bl[nf] = *(const bf16x8*)&owl[r];
        }
#pragma unroll
        for (int mf = 0; mf < 2; ++mf)
#pragma unroll
            for (int nf = 0; nf < 4; ++nf) {
                f32x4 t = acc[mf][nf];
                t = __builtin_amdgcn_mfma_f32_16x16x32_bf16(ah[mf], bh[nf], t, 0, 0, 0);
                t = __builtin_amdgcn_mfma_f32_16x16x32_bf16(al[mf], bh[nf], t, 0, 0, 0);
                t = __builtin_amdgcn_mfma_f32_16x16x32_bf16(ah[mf], bl[nf], t, 0, 0, 0);
                acc[mf][nf] = t;
            }
    }

#pragma unroll
    for (int mf = 0; mf < 2; ++mf)
#pragma unroll
        for (int j = 0; j < 4; ++j) {
            const int tg = t0 + w * 32 + mf * 16 + g * 4 + j;
#pragma unroll
            for (int nf = 0; nf < 4; ++nf)
                out[(size_t)tg * EMB + o0 + nf * 16 + c] =
                    acc[mf][nf][j] + opb[o0 + nf * 16 + c];
        }
}

// =====================================================================
extern "C" void kernel_launch(void* const* d_in, const int* in_sizes, int n_in,
                              void* d_out, int out_size, void* d_ws, size_t ws_size,
                              hipStream_t stream)
{
    const float* query = (const float*)d_in[0];
    const float* key_  = (const float*)d_in[1];
    const float* value = (const float*)d_in[2];
    const float* ipw   = (const float*)d_in[3];
    const float* ipb   = (const float*)d_in[4];
    const float* opw   = (const float*)d_in[5];
    const float* opb   = (const float*)d_in[6];
    // d_in[7] = update_steps_max (0)

    char* ws = (char*)d_ws;
    const size_t MB = 1024 * 1024;
    // [0,24MB): converted inputs (dead after GEMM1; head reused for ao)
    ushort_t* xqh = (ushort_t*)(ws + 0 * MB);
    ushort_t* xql = (ushort_t*)(ws + 4 * MB);
    ushort_t* xkh = (ushort_t*)(ws + 8 * MB);
    ushort_t* xkl = (ushort_t*)(ws + 12 * MB);
    ushort_t* xvh = (ushort_t*)(ws + 16 * MB);
    ushort_t* xvl = (ushort_t*)(ws + 20 * MB);
    // [24,48MB): GEMM1 outputs (attention inputs)
    ushort_t* qhi = (ushort_t*)(ws + 24 * MB);
    ushort_t* qlo = (ushort_t*)(ws + 28 * MB);
    ushort_t* khi = (ushort_t*)(ws + 32 * MB);
    ushort_t* klo = (ushort_t*)(ws + 36 * MB);
    float*    vn  = (float*)   (ws + 40 * MB);   // 8 MB f32
    // [48,54MB): converted weights
    ushort_t* iwh = (ushort_t*)(ws + 48 * MB);   // 1.5 MB
    ushort_t* iwl = (ushort_t*)(ws + 50 * MB);
    ushort_t* owh = (ushort_t*)(ws + 52 * MB);   // 0.5 MB
    ushort_t* owl = (ushort_t*)(ws + 53 * MB);
    // ao (split) reuses the dead converted-input head region
    ushort_t* aoh = (ushort_t*)(ws + 0 * MB);
    ushort_t* aol = (ushort_t*)(ws + 4 * MB);
    float* out = (float*)d_out;
    (void)ws_size;

    convert_split<<<2048, 256, 0, stream>>>(
        query, key_, value, ipw, opw,
        xqh, xql, xkh, xkl, xvh, xvl, iwh, iwl, owh, owl);
    gemm_qkv_ln_mfma<<<dim3(32, 8, 3), 256, 0, stream>>>(
        xqh, xql, xkh, xkl, xvh, xvl, iwh, iwl, ipb, qhi, qlo, khi, klo, vn);
    attn_sparsemax_mfma<<<2048, 512, 0, stream>>>(
        qhi, qlo, khi, klo, vn, aoh, aol);
    gemm_out_mfma<<<dim3(32, 8), 256, 0, stream>>>(
        aoh, aol, owh, owl, opb, out);
}

// Round 4
// 377.622 us; speedup vs baseline: 1.3238x; 1.3238x over previous
//
#include <hip/hip_runtime.h>

#define SEQ   2048
#define BATCH 2
#define EMB   512
#define NH    8

typedef short bf16x8 __attribute__((ext_vector_type(8)));
typedef float f32x4  __attribute__((ext_vector_type(4)));
typedef unsigned short u16;

static __device__ __forceinline__ u16 f2bf(float f) {
    unsigned u = __float_as_uint(f);
    return (u16)((u + 0x7FFF + ((u >> 16) & 1)) >> 16);   // rne
}
static __device__ __forceinline__ float bf2f(u16 h) {
    return __uint_as_float((unsigned)h << 16);
}
static __device__ __forceinline__ unsigned cvtpk(float a, float b) {
    unsigned r;
    asm("v_cvt_pk_bf16_f32 %0, %1, %2" : "=v"(r) : "v"(a), "v"(b));
    return r;   // low16 = bf16(a), high16 = bf16(b), rne
}
// split 8 consecutive f32 into hi/lo bf16x8
static __device__ __forceinline__ void split8(const float* p, bf16x8& hi, bf16x8& lo) {
    const float4 f0 = *(const float4*)p;
    const float4 f1 = *(const float4*)(p + 4);
    const float fv[8] = {f0.x, f0.y, f0.z, f0.w, f1.x, f1.y, f1.z, f1.w};
    union { unsigned w[4]; bf16x8 v; } H, L;
#pragma unroll
    for (int q = 0; q < 4; ++q) {
        const float a = fv[2 * q], b = fv[2 * q + 1];
        const unsigned h = cvtpk(a, b);
        const float la = a - __uint_as_float(h << 16);
        const float lb = b - __uint_as_float(h & 0xFFFF0000u);
        H.w[q] = h;
        L.w[q] = cvtpk(la, lb);
    }
    hi = H.v; lo = L.v;
}

// =====================================================================
// convert_w: split f32 weights -> bf16 hi/lo. 262144 float4 groups.
// =====================================================================
#define IW4 196608
#define W4  262144
__global__ __launch_bounds__(256) void convert_w(
    const float* __restrict__ ipw, const float* __restrict__ opw,
    u16* __restrict__ iwh, u16* __restrict__ iwl,
    u16* __restrict__ owh, u16* __restrict__ owl)
{
    const int f = blockIdx.x * 256 + threadIdx.x;
    if (f >= W4) return;
    const float* src; u16 *dh, *dl; int o;
    if (f < IW4) { src = ipw; dh = iwh; dl = iwl; o = f; }
    else         { src = opw; dh = owh; dl = owl; o = f - IW4; }
    const float4 x = ((const float4*)src)[o];
    ushort4 hi, lo;
    hi.x = f2bf(x.x); lo.x = f2bf(x.x - bf2f(hi.x));
    hi.y = f2bf(x.y); lo.y = f2bf(x.y - bf2f(hi.y));
    hi.z = f2bf(x.z); lo.z = f2bf(x.z - bf2f(hi.z));
    hi.w = f2bf(x.w); lo.w = f2bf(x.w - bf2f(hi.w));
    ((ushort4*)dh)[o] = hi;
    ((ushort4*)dl)[o] = lo;
}

// =====================================================================
// GEMM1 (MFMA): X f32 (in-register split) @ W^T (pre-split) + b -> LN
// z=0: Q*D^-0.5 -> split bf16 [bh][i][d]
// z=1: K        -> split bf16 [bh][i][d]
// z=2: V        -> split bf16 TRANSPOSED [bh][d][j]
// grid (32, 8, 3) block 256 (4 waves); wave: 32 rows x 64 cols.
// =====================================================================
__global__ __launch_bounds__(256, 4) void gemm_qkv_ln_mfma(
    const float* __restrict__ query, const float* __restrict__ key_in,
    const float* __restrict__ value,
    const u16* __restrict__ iwh, const u16* __restrict__ iwl,
    const float* __restrict__ ipb,
    u16* __restrict__ qhi, u16* __restrict__ qlo,
    u16* __restrict__ khi, u16* __restrict__ klo,
    u16* __restrict__ vth, u16* __restrict__ vtl)
{
    const int z = blockIdx.z;
    const float* Xf = (z == 0) ? query : (z == 1) ? key_in : value;
    u16* dh = (z == 0) ? qhi : khi;
    u16* dl = (z == 0) ? qlo : klo;
    const float scale = (z == 0) ? 0.125f : 1.0f;

    const int t0  = blockIdx.x * 128;
    const int h   = blockIdx.y;
    const int og0 = z * EMB + h * 64;

    const int tid = threadIdx.x;
    const int w   = tid >> 6;
    const int l   = tid & 63;
    const int c   = l & 15;
    const int g   = l >> 4;

    f32x4 acc[2][4];
#pragma unroll
    for (int mf = 0; mf < 2; ++mf)
#pragma unroll
        for (int nf = 0; nf < 4; ++nf) acc[mf][nf] = (f32x4){0.f, 0.f, 0.f, 0.f};

    const int arow0 = t0 + w * 32 + c;
#pragma unroll
    for (int ks = 0; ks < 16; ++ks) {
        const int k0 = ks * 32 + g * 8;
        bf16x8 ah[2], al[2], bh[4], bl[4];
#pragma unroll
        for (int mf = 0; mf < 2; ++mf)
            split8(&Xf[(size_t)(arow0 + mf * 16) * EMB + k0], ah[mf], al[mf]);
#pragma unroll
        for (int nf = 0; nf < 4; ++nf) {
            const size_t r = (size_t)(og0 + nf * 16 + c) * EMB + k0;
            bh[nf] = *(const bf16x8*)&iwh[r];
            bl[nf] = *(const bf16x8*)&iwl[r];
        }
#pragma unroll
        for (int mf = 0; mf < 2; ++mf)
#pragma unroll
            for (int nf = 0; nf < 4; ++nf) {
                f32x4 t = acc[mf][nf];
                t = __builtin_amdgcn_mfma_f32_16x16x32_bf16(ah[mf], bh[nf], t, 0, 0, 0);
                t = __builtin_amdgcn_mfma_f32_16x16x32_bf16(al[mf], bh[nf], t, 0, 0, 0);
                t = __builtin_amdgcn_mfma_f32_16x16x32_bf16(ah[mf], bl[nf], t, 0, 0, 0);
                acc[mf][nf] = t;
            }
    }

    // bias
#pragma unroll
    for (int nf = 0; nf < 4; ++nf) {
        const float bj = ipb[og0 + nf * 16 + c];
#pragma unroll
        for (int mf = 0; mf < 2; ++mf)
#pragma unroll
            for (int j = 0; j < 4; ++j) acc[mf][nf][j] += bj;
    }

    // LayerNorm per token row (64 cols = 4 nf x 16 lanes)
#pragma unroll
    for (int mf = 0; mf < 2; ++mf) {
        float mu[4], rs[4];
#pragma unroll
        for (int j = 0; j < 4; ++j) {
            float s = acc[mf][0][j] + acc[mf][1][j] + acc[mf][2][j] + acc[mf][3][j];
#pragma unroll
            for (int d = 1; d <= 8; d <<= 1) s += __shfl_xor(s, d);
            mu[j] = s * (1.0f / 64.0f);
        }
#pragma unroll
        for (int j = 0; j < 4; ++j) {
            float t = 0.f;
#pragma unroll
            for (int nf = 0; nf < 4; ++nf) {
                const float dv = acc[mf][nf][j] - mu[j];
                t += dv * dv;
            }
#pragma unroll
            for (int d = 1; d <= 8; d <<= 1) t += __shfl_xor(t, d);
            rs[j] = rsqrtf(t * (1.0f / 64.0f) + 1e-5f) * scale;
        }
#pragma unroll
        for (int j = 0; j < 4; ++j) {
            const int tg = t0 + w * 32 + mf * 16 + g * 4 + j;
            const int ii = tg >> 1;
            const int b  = tg & 1;
            const int bh_ = b * NH + h;
#pragma unroll
            for (int nf = 0; nf < 4; ++nf) {
                const float val = (acc[mf][nf][j] - mu[j]) * rs[j];
                const u16 hi = f2bf(val);
                const u16 lo = f2bf(val - bf2f(hi));
                if (z == 2) {
                    // transposed: [bh][d][j-token]
                    const size_t a = ((size_t)bh_ * 64 + nf * 16 + c) * SEQ + ii;
                    vth[a] = hi; vtl[a] = lo;
                } else {
                    const size_t a = ((size_t)bh_ * SEQ + ii) * 64 + nf * 16 + c;
                    dh[a] = hi; dl[a] = lo;
                }
            }
        }
    }
}

// =====================================================================
// Fused attention: swapped QK^T (S^T layout) -> Michelot sparsemax ->
// dense split-bf16 PV via MFMA (bpermute P-transpose) -> ao split bf16.
// grid 1024 (XCD-pinned: xcd=wgid&7 handles bh=2*xcd then 2*xcd+1),
// block 512 (8 waves). Block = 32 q-rows; wave w = key cols w*256..+256.
// =====================================================================
__global__ __launch_bounds__(512, 2) void attn_sparsemax_mfma(
    const u16* __restrict__ qhi, const u16* __restrict__ qlo,
    const u16* __restrict__ khi, const u16* __restrict__ klo,
    const u16* __restrict__ vth, const u16* __restrict__ vtl,
    u16* __restrict__ aoh, u16* __restrict__ aol)
{
    __shared__ float Opart[8][16][65];
    __shared__ float wred[8][32];
    __shared__ float wcnt[8][32];

    const int tid = threadIdx.x;
    const int w   = tid >> 6;
    const int l   = tid & 63;
    const int c   = l & 15;
    const int g   = l >> 4;

    const int wgid = blockIdx.x;
    const int xcd  = wgid & 7;
    const int idx  = wgid >> 3;            // 0..127 in XCD-local order
    const int bh   = xcd * 2 + (idx >> 6); // one bh working set at a time
    const int q0   = (idx & 63) * 32;

    const size_t bhoff = (size_t)bh * SEQ * 64;
    const u16* qh = qhi + bhoff;
    const u16* ql = qlo + bhoff;
    const u16* kh = khi + bhoff;
    const u16* kl = klo + bhoff;
    const u16* vh_ = vth + bhoff;          // [64][2048] layout
    const u16* vl_ = vtl + bhoff;

    // ---- Q B-fragments: B[k=d, n=i] = Q[i, d]; nf picks i-block ----
    bf16x8 qhf[2][2], qlf[2][2];           // [nf][kf]
#pragma unroll
    for (int nf = 0; nf < 2; ++nf)
#pragma unroll
        for (int kf = 0; kf < 2; ++kf) {
            const size_t a = (size_t)(q0 + nf * 16 + c) * 64 + kf * 32 + g * 8;
            qhf[nf][kf] = *(const bf16x8*)&qh[a];
            qlf[nf][kf] = *(const bf16x8*)&ql[a];
        }

    // ---- S^T = K @ Q^T : acc[mf][nf], C[row=j-sub, col=i] ----
    const int wbase = w * 256;
    f32x4 acc[16][2];
#pragma unroll
    for (int mf = 0; mf < 16; ++mf) {
        const size_t kr = (size_t)(wbase + mf * 16 + c) * 64 + g * 8;
        const bf16x8 kh0 = *(const bf16x8*)&kh[kr];
        const bf16x8 kh1 = *(const bf16x8*)&kh[kr + 32];
        const bf16x8 kl0 = *(const bf16x8*)&kl[kr];
        const bf16x8 kl1 = *(const bf16x8*)&kl[kr + 32];
#pragma unroll
        for (int nf = 0; nf < 2; ++nf) {
            f32x4 t = (f32x4){0.f, 0.f, 0.f, 0.f};
            t = __builtin_amdgcn_mfma_f32_16x16x32_bf16(kh0, qhf[nf][0], t, 0, 0, 0);
            t = __builtin_amdgcn_mfma_f32_16x16x32_bf16(kh1, qhf[nf][1], t, 0, 0, 0);
            t = __builtin_amdgcn_mfma_f32_16x16x32_bf16(kl0, qhf[nf][0], t, 0, 0, 0);
            t = __builtin_amdgcn_mfma_f32_16x16x32_bf16(kl1, qhf[nf][1], t, 0, 0, 0);
            t = __builtin_amdgcn_mfma_f32_16x16x32_bf16(kh0, qlf[nf][0], t, 0, 0, 0);
            t = __builtin_amdgcn_mfma_f32_16x16x32_bf16(kh1, qlf[nf][1], t, 0, 0, 0);
            acc[mf][nf] = t;
        }
    }

    // ---- row max over j (per lane: i = nf*16+c, 64 j-values) ----
    float tau[2];
    {
        float mx[2];
#pragma unroll
        for (int nf = 0; nf < 2; ++nf) {
            float m = -1e30f;
#pragma unroll
            for (int mf = 0; mf < 16; ++mf)
#pragma unroll
                for (int r = 0; r < 4; ++r) m = fmaxf(m, acc[mf][nf][r]);
            m = fmaxf(m, __shfl_xor(m, 16));
            m = fmaxf(m, __shfl_xor(m, 32));
            mx[nf] = m;
        }
        if (g == 0) {
            wred[w][c]      = mx[0];
            wred[w][16 + c] = mx[1];
        }
    }
    __syncthreads();
#pragma unroll
    for (int nf = 0; nf < 2; ++nf) {
        float m = -1e30f;
#pragma unroll
        for (int ww = 0; ww < 8; ++ww) m = fmaxf(m, wred[ww][nf * 16 + c]);
        tau[nf] = m - 1.0f;            // tau* >= max-1
    }

    // ---- Michelot fixed point ----
    int cprev[2] = {-1, -1};
    for (int it = 0; it < 24; ++it) {
        __syncthreads();               // protect wred/wcnt overwrite
        float sj[2], cj[2];
#pragma unroll
        for (int nf = 0; nf < 2; ++nf) {
            float s = 0.f, cn = 0.f;
#pragma unroll
            for (int mf = 0; mf < 16; ++mf)
#pragma unroll
                for (int r = 0; r < 4; ++r) {
                    const float v = acc[mf][nf][r];
                    if (v > tau[nf]) { s += v; cn += 1.f; }
                }
            s  += __shfl_xor(s, 16);  cn += __shfl_xor(cn, 16);
            s  += __shfl_xor(s, 32);  cn += __shfl_xor(cn, 32);
            sj[nf] = s; cj[nf] = cn;
        }
        if (g == 0) {
#pragma unroll
            for (int nf = 0; nf < 2; ++nf) {
                wred[w][nf * 16 + c] = sj[nf];
                wcnt[w][nf * 16 + c] = cj[nf];
            }
        }
        __syncthreads();
        int changed = 0;
#pragma unroll
        for (int nf = 0; nf < 2; ++nf) {
            float S = 0.f, C = 0.f;
#pragma unroll
            for (int ww = 0; ww < 8; ++ww) {
                S += wred[ww][nf * 16 + c];
                C += wcnt[ww][nf * 16 + c];
            }
            tau[nf] = (S - 1.0f) / C;
            const int Ci = (int)C;
            changed |= (Ci != cprev[nf]);
            cprev[nf] = Ci;
        }
        if (!__any(changed)) break;
    }

    // ---- dense PV: out^T[d,i] = sum_j V^T[d,j] * P^T[j,i] ----
    const int a1 = ((2 * (g & 1)) * 16 + c) * 4;   // bpermute byte addrs
    const int a2 = a1 + 64;
    const bool hi_half = (g >> 1);

    f32x4 Oacc[4][2];
#pragma unroll
    for (int mo = 0; mo < 4; ++mo)
#pragma unroll
        for (int nf = 0; nf < 2; ++nf) Oacc[mo][nf] = (f32x4){0.f, 0.f, 0.f, 0.f};

#pragma unroll
    for (int ks = 0; ks < 8; ++ks) {
        // source-side: P split hi/lo, pair-packed, for frags 2ks, 2ks+1
        unsigned Ha[2][2], La[2][2], Hb[2][2], Lb[2][2];   // [nf][word]
#pragma unroll
        for (int m01 = 0; m01 < 2; ++m01) {
            const int mf = 2 * ks + m01;
#pragma unroll
            for (int nf = 0; nf < 2; ++nf) {
                const f32x4 s = acc[mf][nf];
                const float p0 = fmaxf(s[0] - tau[nf], 0.f);
                const float p1 = fmaxf(s[1] - tau[nf], 0.f);
                const float p2 = fmaxf(s[2] - tau[nf], 0.f);
                const float p3 = fmaxf(s[3] - tau[nf], 0.f);
                const unsigned h0 = cvtpk(p0, p1);
                const unsigned h1 = cvtpk(p2, p3);
                const unsigned l0 = cvtpk(p0 - __uint_as_float(h0 << 16),
                                          p1 - __uint_as_float(h0 & 0xFFFF0000u));
                const unsigned l1 = cvtpk(p2 - __uint_as_float(h1 << 16),
                                          p3 - __uint_as_float(h1 & 0xFFFF0000u));
                if (m01 == 0) { Ha[nf][0] = h0; Ha[nf][1] = h1; La[nf][0] = l0; La[nf][1] = l1; }
                else          { Hb[nf][0] = h0; Hb[nf][1] = h1; Lb[nf][0] = l0; Lb[nf][1] = l1; }
            }
        }
        // build B-frags via 2x bpermute + select
        bf16x8 Bhi[2], Blo[2];
#pragma unroll
        for (int nf = 0; nf < 2; ++nf) {
            union { int w4[4]; bf16x8 v; } BH, BL;
#pragma unroll
            for (int q = 0; q < 2; ++q) {
                const int ha = __builtin_amdgcn_ds_bpermute(a1, (int)Ha[nf][q]);
                const int hb = __builtin_amdgcn_ds_bpermute(a1, (int)Hb[nf][q]);
                BH.w4[q] = hi_half ? hb : ha;
                const int ha2 = __builtin_amdgcn_ds_bpermute(a2, (int)Ha[nf][q]);
                const int hb2 = __builtin_amdgcn_ds_bpermute(a2, (int)Hb[nf][q]);
                BH.w4[2 + q] = hi_half ? hb2 : ha2;
                const int la = __builtin_amdgcn_ds_bpermute(a1, (int)La[nf][q]);
                const int lb = __builtin_amdgcn_ds_bpermute(a1, (int)Lb[nf][q]);
                BL.w4[q] = hi_half ? lb : la;
                const int la2 = __builtin_amdgcn_ds_bpermute(a2, (int)La[nf][q]);
                const int lb2 = __builtin_amdgcn_ds_bpermute(a2, (int)Lb[nf][q]);
                BL.w4[2 + q] = hi_half ? lb2 : la2;
            }
            Bhi[nf] = BH.v; Blo[nf] = BL.v;
        }
        // V^T A-frags + MFMA
#pragma unroll
        for (int mo = 0; mo < 4; ++mo) {
            const size_t va = (size_t)(mo * 16 + c) * SEQ + wbase + ks * 32 + g * 8;
            const bf16x8 vh = *(const bf16x8*)&vh_[va];
            const bf16x8 vl = *(const bf16x8*)&vl_[va];
#pragma unroll
            for (int nf = 0; nf < 2; ++nf) {
                f32x4 t = Oacc[mo][nf];
                t = __builtin_amdgcn_mfma_f32_16x16x32_bf16(vh, Bhi[nf], t, 0, 0, 0);
                t = __builtin_amdgcn_mfma_f32_16x16x32_bf16(vh, Blo[nf], t, 0, 0, 0);
                t = __builtin_amdgcn_mfma_f32_16x16x32_bf16(vl, Bhi[nf], t, 0, 0, 0);
                Oacc[mo][nf] = t;
            }
        }
    }

    // ---- cross-wave reduce (two nf phases, LDS [8][16][65]) ----
    const int b_ = bh >> 3, h_ = bh & 7;
#pragma unroll
    for (int nf = 0; nf < 2; ++nf) {
        if (nf) __syncthreads();       // protect phase-0 reads
#pragma unroll
        for (int mo = 0; mo < 4; ++mo)
#pragma unroll
            for (int r = 0; r < 4; ++r)
                Opart[w][c][mo * 16 + 4 * g + r] = Oacc[mo][nf][r];
        __syncthreads();
        // reduce 16 i x 64 d
#pragma unroll
        for (int p = 0; p < 2; ++p) {
            const int idx2 = p * 512 + tid;      // 0..1023
            const int d = idx2 & 63;
            const int i = idx2 >> 6;             // 0..15
            float sv = 0.f;
#pragma unroll
            for (int ww = 0; ww < 8; ++ww) sv += Opart[ww][i][d];
            const int irow = q0 + nf * 16 + i;
            const size_t oa = (size_t)(irow * BATCH + b_) * EMB + h_ * 64 + d;
            const u16 hv = f2bf(sv);
            aoh[oa] = hv;
            aol[oa] = f2bf(sv - bf2f(hv));
        }
    }
}

// =====================================================================
// GEMM2 (MFMA, split): ao @ opw^T + opb -> d_out f32. grid (32,8) blk 256.
// =====================================================================
__global__ __launch_bounds__(256, 4) void gemm_out_mfma(
    const u16* __restrict__ aoh, const u16* __restrict__ aol,
    const u16* __restrict__ owh, const u16* __restrict__ owl,
    const float* __restrict__ opb, float* __restrict__ out)
{
    const int t0 = blockIdx.x * 128;
    const int o0 = blockIdx.y * 64;

    const int tid = threadIdx.x;
    const int w   = tid >> 6;
    const int l   = tid & 63;
    const int c   = l & 15;
    const int g   = l >> 4;

    f32x4 acc[2][4];
#pragma unroll
    for (int mf = 0; mf < 2; ++mf)
#pragma unroll
        for (int nf = 0; nf < 4; ++nf) acc[mf][nf] = (f32x4){0.f, 0.f, 0.f, 0.f};

    const int arow0 = t0 + w * 32 + c;
#pragma unroll
    for (int ks = 0; ks < 16; ++ks) {
        const int k0 = ks * 32 + g * 8;
        bf16x8 ah[2], al[2], bh[4], bl[4];
#pragma unroll
        for (int mf = 0; mf < 2; ++mf) {
            const size_t r = (size_t)(arow0 + mf * 16) * EMB + k0;
            ah[mf] = *(const bf16x8*)&aoh[r];
            al[mf] = *(const bf16x8*)&aol[r];
        }
#pragma unroll
        for (int nf = 0; nf < 4; ++nf) {
            const size_t r = (size_t)(o0 + nf * 16 + c) * EMB + k0;
            bh[nf] = *(const bf16x8*)&owh[r];
            bl[nf] = *(const bf16x8*)&owl[r];
        }
#pragma unroll
        for (int mf = 0; mf < 2; ++mf)
#pragma unroll
            for (int nf = 0; nf < 4; ++nf) {
                f32x4 t = acc[mf][nf];
                t = __builtin_amdgcn_mfma_f32_16x16x32_bf16(ah[mf], bh[nf], t, 0, 0, 0);
                t = __builtin_amdgcn_mfma_f32_16x16x32_bf16(al[mf], bh[nf], t, 0, 0, 0);
                t = __builtin_amdgcn_mfma_f32_16x16x32_bf16(ah[mf], bl[nf], t, 0, 0, 0);
                acc[mf][nf] = t;
            }
    }

#pragma unroll
    for (int mf = 0; mf < 2; ++mf)
#pragma unroll
        for (int j = 0; j < 4; ++j) {
            const int tg = t0 + w * 32 + mf * 16 + g * 4 + j;
#pragma unroll
            for (int nf = 0; nf < 4; ++nf)
                out[(size_t)tg * EMB + o0 + nf * 16 + c] =
                    acc[mf][nf][j] + opb[o0 + nf * 16 + c];
        }
}

// =====================================================================
extern "C" void kernel_launch(void* const* d_in, const int* in_sizes, int n_in,
                              void* d_out, int out_size, void* d_ws, size_t ws_size,
                              hipStream_t stream)
{
    const float* query = (const float*)d_in[0];
    const float* key_  = (const float*)d_in[1];
    const float* value = (const float*)d_in[2];
    const float* ipw   = (const float*)d_in[3];
    const float* ipb   = (const float*)d_in[4];
    const float* opw   = (const float*)d_in[5];
    const float* opb   = (const float*)d_in[6];
    // d_in[7] = update_steps_max (0)

    char* ws = (char*)d_ws;
    const size_t MB = 1024 * 1024;
    u16* qhi = (u16*)(ws + 0 * MB);    // 4 MB each (16*2048*64 bf16)
    u16* qlo = (u16*)(ws + 4 * MB);
    u16* khi = (u16*)(ws + 8 * MB);
    u16* klo = (u16*)(ws + 12 * MB);
    u16* vth = (u16*)(ws + 16 * MB);   // transposed V [bh][64][2048]
    u16* vtl = (u16*)(ws + 20 * MB);
    u16* aoh = (u16*)(ws + 24 * MB);
    u16* aol = (u16*)(ws + 28 * MB);
    u16* iwh = (u16*)(ws + 32 * MB);   // 1.5 MB
    u16* iwl = (u16*)(ws + 34 * MB);
    u16* owh = (u16*)(ws + 36 * MB);   // 0.5 MB
    u16* owl = (u16*)(ws + 37 * MB);
    float* out = (float*)d_out;
    (void)ws_size; (void)in_sizes; (void)n_in; (void)out_size;

    convert_w<<<1024, 256, 0, stream>>>(ipw, opw, iwh, iwl, owh, owl);
    gemm_qkv_ln_mfma<<<dim3(32, 8, 3), 256, 0, stream>>>(
        query, key_, value, iwh, iwl, ipb, qhi, qlo, khi, klo, vth, vtl);
    attn_sparsemax_mfma<<<1024, 512, 0, stream>>>(
        qhi, qlo, khi, klo, vth, vtl, aoh, aol);
    gemm_out_mfma<<<dim3(32, 8), 256, 0, stream>>>(
        aoh, aol, owh, owl, opb, out);
}

// Round 6
// 369.242 us; speedup vs baseline: 1.3539x; 1.0227x over previous
//
#include <hip/hip_runtime.h>

#define SEQ   2048
#define BATCH 2
#define EMB   512
#define NH    8

typedef short bf16x8 __attribute__((ext_vector_type(8)));
typedef float f32x4  __attribute__((ext_vector_type(4)));
typedef unsigned short u16;
typedef unsigned long long u64;

static __device__ __forceinline__ u16 f2bf(float f) {
    unsigned u = __float_as_uint(f);
    return (u16)((u + 0x7FFF + ((u >> 16) & 1)) >> 16);   // rne
}
static __device__ __forceinline__ float bf2f(u16 h) {
    return __uint_as_float((unsigned)h << 16);
}
static __device__ __forceinline__ unsigned cvtpk(float a, float b) {
    unsigned r;
    asm("v_cvt_pk_bf16_f32 %0, %1, %2" : "=v"(r) : "v"(a), "v"(b));
    return r;   // low16 = bf16(a), high16 = bf16(b), rne
}
// split 8 consecutive f32 into hi/lo bf16x8
static __device__ __forceinline__ void split8(const float* p, bf16x8& hi, bf16x8& lo) {
    const float4 f0 = *(const float4*)p;
    const float4 f1 = *(const float4*)(p + 4);
    const float fv[8] = {f0.x, f0.y, f0.z, f0.w, f1.x, f1.y, f1.z, f1.w};
    union { unsigned w[4]; bf16x8 v; } H, L;
#pragma unroll
    for (int q = 0; q < 4; ++q) {
        const float a = fv[2 * q], b = fv[2 * q + 1];
        const unsigned h = cvtpk(a, b);
        const float la = a - __uint_as_float(h << 16);
        const float lb = b - __uint_as_float(h & 0xFFFF0000u);
        H.w[q] = h;
        L.w[q] = cvtpk(la, lb);
    }
    hi = H.v; lo = L.v;
}

// =====================================================================
// convert_w: split f32 weights -> bf16 hi/lo. 262144 float4 groups.
// =====================================================================
#define IW4 196608
#define W4  262144
__global__ __launch_bounds__(256) void convert_w(
    const float* __restrict__ ipw, const float* __restrict__ opw,
    u16* __restrict__ iwh, u16* __restrict__ iwl,
    u16* __restrict__ owh, u16* __restrict__ owl)
{
    const int f = blockIdx.x * 256 + threadIdx.x;
    if (f >= W4) return;
    const float* src; u16 *dh, *dl; int o;
    if (f < IW4) { src = ipw; dh = iwh; dl = iwl; o = f; }
    else         { src = opw; dh = owh; dl = owl; o = f - IW4; }
    const float4 x = ((const float4*)src)[o];
    ushort4 hi, lo;
    hi.x = f2bf(x.x); lo.x = f2bf(x.x - bf2f(hi.x));
    hi.y = f2bf(x.y); lo.y = f2bf(x.y - bf2f(hi.y));
    hi.z = f2bf(x.z); lo.z = f2bf(x.z - bf2f(hi.z));
    hi.w = f2bf(x.w); lo.w = f2bf(x.w - bf2f(hi.w));
    ((ushort4*)dh)[o] = hi;
    ((ushort4*)dl)[o] = lo;
}

// =====================================================================
// GEMM1 (MFMA): X f32 (in-register split) @ W^T (pre-split) + b -> LN
// z=0: Q*D^-0.5 -> split bf16 [bh][i][d]
// z=1: K        -> split bf16 [bh][i][d]
// z=2: V        -> split bf16 TRANSPOSED [bh][d][j]
// grid (32, 8, 3) block 256 (4 waves); wave: 32 rows x 64 cols.
// Epilogue stages the 128x64 tile in LDS -> fully coalesced stores.
// =====================================================================
__global__ __launch_bounds__(256, 4) void gemm_qkv_ln_mfma(
    const float* __restrict__ query, const float* __restrict__ key_in,
    const float* __restrict__ value,
    const u16* __restrict__ iwh, const u16* __restrict__ iwl,
    const float* __restrict__ ipb,
    u16* __restrict__ qhi, u16* __restrict__ qlo,
    u16* __restrict__ khi, u16* __restrict__ klo,
    u16* __restrict__ vth, u16* __restrict__ vtl)
{
    __shared__ float Et[8704];   // [128][68] f32 (z<2)  or  [64][133] (z==2)

    const int z = blockIdx.z;
    const float* Xf = (z == 0) ? query : (z == 1) ? key_in : value;
    const float scale = (z == 0) ? 0.125f : 1.0f;

    const int t0  = blockIdx.x * 128;
    const int h   = blockIdx.y;
    const int og0 = z * EMB + h * 64;

    const int tid = threadIdx.x;
    const int w   = tid >> 6;
    const int l   = tid & 63;
    const int c   = l & 15;
    const int g   = l >> 4;

    f32x4 acc[2][4];
#pragma unroll
    for (int mf = 0; mf < 2; ++mf)
#pragma unroll
        for (int nf = 0; nf < 4; ++nf) acc[mf][nf] = (f32x4){0.f, 0.f, 0.f, 0.f};

    const int arow0 = t0 + w * 32 + c;
#pragma unroll
    for (int ks = 0; ks < 16; ++ks) {
        const int k0 = ks * 32 + g * 8;
        bf16x8 ah[2], al[2], bh[4], bl[4];
#pragma unroll
        for (int mf = 0; mf < 2; ++mf)
            split8(&Xf[(size_t)(arow0 + mf * 16) * EMB + k0], ah[mf], al[mf]);
#pragma unroll
        for (int nf = 0; nf < 4; ++nf) {
            const size_t r = (size_t)(og0 + nf * 16 + c) * EMB + k0;
            bh[nf] = *(const bf16x8*)&iwh[r];
            bl[nf] = *(const bf16x8*)&iwl[r];
        }
#pragma unroll
        for (int mf = 0; mf < 2; ++mf)
#pragma unroll
            for (int nf = 0; nf < 4; ++nf) {
                f32x4 t = acc[mf][nf];
                t = __builtin_amdgcn_mfma_f32_16x16x32_bf16(ah[mf], bh[nf], t, 0, 0, 0);
                t = __builtin_amdgcn_mfma_f32_16x16x32_bf16(al[mf], bh[nf], t, 0, 0, 0);
                t = __builtin_amdgcn_mfma_f32_16x16x32_bf16(ah[mf], bl[nf], t, 0, 0, 0);
                acc[mf][nf] = t;
            }
    }

    // bias
#pragma unroll
    for (int nf = 0; nf < 4; ++nf) {
        const float bj = ipb[og0 + nf * 16 + c];
#pragma unroll
        for (int mf = 0; mf < 2; ++mf)
#pragma unroll
            for (int j = 0; j < 4; ++j) acc[mf][nf][j] += bj;
    }

    // LayerNorm per token row + stage to LDS
#pragma unroll
    for (int mf = 0; mf < 2; ++mf) {
        float mu[4], rs[4];
#pragma unroll
        for (int j = 0; j < 4; ++j) {
            float s = acc[mf][0][j] + acc[mf][1][j] + acc[mf][2][j] + acc[mf][3][j];
#pragma unroll
            for (int d = 1; d <= 8; d <<= 1) s += __shfl_xor(s, d);
            mu[j] = s * (1.0f / 64.0f);
        }
#pragma unroll
        for (int j = 0; j < 4; ++j) {
            float t = 0.f;
#pragma unroll
            for (int nf = 0; nf < 4; ++nf) {
                const float dv = acc[mf][nf][j] - mu[j];
                t += dv * dv;
            }
#pragma unroll
            for (int d = 1; d <= 8; d <<= 1) t += __shfl_xor(t, d);
            rs[j] = rsqrtf(t * (1.0f / 64.0f) + 1e-5f) * scale;
        }
#pragma unroll
        for (int j = 0; j < 4; ++j) {
            const int tl = w * 32 + mf * 16 + g * 4 + j;   // 0..127
#pragma unroll
            for (int nf = 0; nf < 4; ++nf) {
                const float val = (acc[mf][nf][j] - mu[j]) * rs[j];
                const int o = nf * 16 + c;                 // 0..63
                if (z == 2) Et[o * 133 + tl] = val;        // [d][tok]
                else        Et[tl * 68 + o]  = val;        // [tok][d]
            }
        }
    }
    __syncthreads();

    // coalesced store phase: 256 segments x 128 B, 8 threads per segment
    const int part = tid & 7;
    if (z < 2) {
        u16* dh = (z == 0) ? qhi : khi;
        u16* dl = (z == 0) ? qlo : klo;
#pragma unroll
        for (int p = 0; p < 8; ++p) {
            const int seg = p * 32 + (tid >> 3);
            const int tl  = seg & 127;
            const int hl  = seg >> 7;
            const float4 v0 = *(const float4*)&Et[tl * 68 + part * 8];
            const float4 v1 = *(const float4*)&Et[tl * 68 + part * 8 + 4];
            const float vv[8] = {v0.x, v0.y, v0.z, v0.w, v1.x, v1.y, v1.z, v1.w};
            unsigned pk[4];
#pragma unroll
            for (int q = 0; q < 4; ++q) {
                u16 ua, ub;
                if (hl == 0) { ua = f2bf(vv[2*q]); ub = f2bf(vv[2*q+1]); }
                else {
                    const u16 ha = f2bf(vv[2*q]),  hb = f2bf(vv[2*q+1]);
                    ua = f2bf(vv[2*q] - bf2f(ha)); ub = f2bf(vv[2*q+1] - bf2f(hb));
                }
                pk[q] = (unsigned)ua | ((unsigned)ub << 16);
            }
            const int bh_ = (tl & 1) * NH + h;
            const int ii  = (t0 >> 1) + (tl >> 1);
            u16* dst = hl ? dl : dh;
            *(uint4*)&dst[((size_t)bh_ * SEQ + ii) * 64 + part * 8] =
                make_uint4(pk[0], pk[1], pk[2], pk[3]);
        }
    } else {
#pragma unroll
        for (int p = 0; p < 8; ++p) {
            const int seg  = p * 32 + (tid >> 3);
            const int d    = seg & 63;
            const int rest = seg >> 6;
            const int b    = rest & 1;
            const int hl   = rest >> 1;
            float vv[8];
#pragma unroll
            for (int k = 0; k < 8; ++k)
                vv[k] = Et[d * 133 + 2 * (part * 8 + k) + b];
            unsigned pk[4];
#pragma unroll
            for (int q = 0; q < 4; ++q) {
                u16 ua, ub;
                if (hl == 0) { ua = f2bf(vv[2*q]); ub = f2bf(vv[2*q+1]); }
                else {
                    const u16 ha = f2bf(vv[2*q]),  hb = f2bf(vv[2*q+1]);
                    ua = f2bf(vv[2*q] - bf2f(ha)); ub = f2bf(vv[2*q+1] - bf2f(hb));
                }
                pk[q] = (unsigned)ua | ((unsigned)ub << 16);
            }
            const int bh_ = b * NH + h;
            u16* dst = hl ? vtl : vth;
            *(uint4*)&dst[((size_t)bh_ * 64 + d) * SEQ + (t0 >> 1) + part * 8] =
                make_uint4(pk[0], pk[1], pk[2], pk[3]);
        }
    }
}

// =====================================================================
// Fused attention: swapped QK^T (S^T layout) -> Michelot sparsemax
// (double-buffered reduce, 1 barrier/iter) -> dense split-bf16 PV with
// wave-private LDS P-transpose -> ao split bf16.
// grid 1024 (XCD-pinned)  block 512 (8 waves).
// =====================================================================
__global__ __launch_bounds__(512, 2) void attn_sparsemax_mfma(
    const u16* __restrict__ qhi, const u16* __restrict__ qlo,
    const u16* __restrict__ khi, const u16* __restrict__ klo,
    const u16* __restrict__ vth, const u16* __restrict__ vtl,
    u16* __restrict__ aoh, u16* __restrict__ aol)
{
    __shared__ float Opart[8][16][66];     // stride 66 -> 2-way max on write
    __shared__ u16   Pst[8][2][16][40];    // wave-private P^T staging (hi/lo)
    __shared__ float wred[2][8][32];       // double-buffered Michelot reduce
    __shared__ float wcnt[2][8][32];

    const int tid = threadIdx.x;
    const int w   = tid >> 6;
    const int l   = tid & 63;
    const int c   = l & 15;
    const int g   = l >> 4;

    const int wgid = blockIdx.x;
    const int xcd  = wgid & 7;
    const int idx  = wgid >> 3;            // 0..127 XCD-local order
    const int bh   = xcd * 2 + (idx >> 6); // one bh working set at a time
    const int q0   = (idx & 63) * 32;

    const size_t bhoff = (size_t)bh * SEQ * 64;
    const u16* qh  = qhi + bhoff;
    const u16* ql  = qlo + bhoff;
    const u16* kh  = khi + bhoff;
    const u16* kl  = klo + bhoff;
    const u16* vh_ = vth + bhoff;          // [64][2048]
    const u16* vl_ = vtl + bhoff;

    // Q B-fragments
    bf16x8 qhf[2][2], qlf[2][2];
#pragma unroll
    for (int nf = 0; nf < 2; ++nf)
#pragma unroll
        for (int kf = 0; kf < 2; ++kf) {
            const size_t a = (size_t)(q0 + nf * 16 + c) * 64 + kf * 32 + g * 8;
            qhf[nf][kf] = *(const bf16x8*)&qh[a];
            qlf[nf][kf] = *(const bf16x8*)&ql[a];
        }

    // S^T = K @ Q^T
    const int wbase = w * 256;
    f32x4 acc[16][2];
#pragma unroll
    for (int mf = 0; mf < 16; ++mf) {
        const size_t kr = (size_t)(wbase + mf * 16 + c) * 64 + g * 8;
        const bf16x8 kh0 = *(const bf16x8*)&kh[kr];
        const bf16x8 kh1 = *(const bf16x8*)&kh[kr + 32];
        const bf16x8 kl0 = *(const bf16x8*)&kl[kr];
        const bf16x8 kl1 = *(const bf16x8*)&kl[kr + 32];
#pragma unroll
        for (int nf = 0; nf < 2; ++nf) {
            f32x4 t = (f32x4){0.f, 0.f, 0.f, 0.f};
            t = __builtin_amdgcn_mfma_f32_16x16x32_bf16(kh0, qhf[nf][0], t, 0, 0, 0);
            t = __builtin_amdgcn_mfma_f32_16x16x32_bf16(kh1, qhf[nf][1], t, 0, 0, 0);
            t = __builtin_amdgcn_mfma_f32_16x16x32_bf16(kl0, qhf[nf][0], t, 0, 0, 0);
            t = __builtin_amdgcn_mfma_f32_16x16x32_bf16(kl1, qhf[nf][1], t, 0, 0, 0);
            t = __builtin_amdgcn_mfma_f32_16x16x32_bf16(kh0, qlf[nf][0], t, 0, 0, 0);
            t = __builtin_amdgcn_mfma_f32_16x16x32_bf16(kh1, qlf[nf][1], t, 0, 0, 0);
            acc[mf][nf] = t;
        }
    }

    // row max -> wred[0]
    {
        float mx[2];
#pragma unroll
        for (int nf = 0; nf < 2; ++nf) {
            float m = -1e30f;
#pragma unroll
            for (int mf = 0; mf < 16; ++mf)
#pragma unroll
                for (int r = 0; r < 4; ++r) m = fmaxf(m, acc[mf][nf][r]);
            m = fmaxf(m, __shfl_xor(m, 16));
            m = fmaxf(m, __shfl_xor(m, 32));
            mx[nf] = m;
        }
        if (g == 0) { wred[0][w][c] = mx[0]; wred[0][w][16 + c] = mx[1]; }
    }
    __syncthreads();

    float tau[2];
#pragma unroll
    for (int nf = 0; nf < 2; ++nf) {
        float m = -1e30f;
#pragma unroll
        for (int ww = 0; ww < 8; ++ww) m = fmaxf(m, wred[0][ww][nf * 16 + c]);
        tau[nf] = m - 1.0f;            // tau* >= max-1
    }

    // Michelot fixed point: 1 barrier/iter via double buffering
    int cprev[2] = {-1, -1};
    for (int it = 0; it < 24; ++it) {
        const int bs = (~it) & 1;      // 1,0,1,0,...
        float sj[2], cj[2];
#pragma unroll
        for (int nf = 0; nf < 2; ++nf) {
            float s = 0.f, cn = 0.f;
#pragma unroll
            for (int mf = 0; mf < 16; ++mf)
#pragma unroll
                for (int r = 0; r < 4; ++r) {
                    const float v = acc[mf][nf][r];
                    if (v > tau[nf]) { s += v; cn += 1.f; }
                }
            s  += __shfl_xor(s, 16);  cn += __shfl_xor(cn, 16);
            s  += __shfl_xor(s, 32);  cn += __shfl_xor(cn, 32);
            sj[nf] = s; cj[nf] = cn;
        }
        if (g == 0) {
            wred[bs][w][c]      = sj[0];  wred[bs][w][16 + c] = sj[1];
            wcnt[bs][w][c]      = cj[0];  wcnt[bs][w][16 + c] = cj[1];
        }
        __syncthreads();
        int changed = 0;
#pragma unroll
        for (int nf = 0; nf < 2; ++nf) {
            float S = 0.f, C = 0.f;
#pragma unroll
            for (int ww = 0; ww < 8; ++ww) {
                S += wred[bs][ww][nf * 16 + c];
                C += wcnt[bs][ww][nf * 16 + c];
            }
            tau[nf] = (S - 1.0f) / C;
            const int Ci = (int)C;
            changed |= (Ci != cprev[nf]);
            cprev[nf] = Ci;
        }
        if (!__any(changed)) break;
    }

    // dense PV: out^T[d,i] = sum_j V^T[d,j] * P^T[j,i]
    // P^T transpose via wave-private LDS: write [i][j32], read B-frags back.
    f32x4 Oacc[4][2];
#pragma unroll
    for (int mo = 0; mo < 4; ++mo)
#pragma unroll
        for (int nf = 0; nf < 2; ++nf) Oacc[mo][nf] = (f32x4){0.f, 0.f, 0.f, 0.f};

#pragma unroll
    for (int ks = 0; ks < 8; ++ks) {
        bf16x8 vh[4], vl[4];
#pragma unroll
        for (int mo = 0; mo < 4; ++mo) {
            const size_t va = (size_t)(mo * 16 + c) * SEQ + wbase + ks * 32 + g * 8;
            vh[mo] = *(const bf16x8*)&vh_[va];
            vl[mo] = *(const bf16x8*)&vl_[va];
        }
#pragma unroll
        for (int nf = 0; nf < 2; ++nf) {
#pragma unroll
            for (int m01 = 0; m01 < 2; ++m01) {
                const f32x4 s = acc[2 * ks + m01][nf];
                const float p0 = fmaxf(s[0] - tau[nf], 0.f);
                const float p1 = fmaxf(s[1] - tau[nf], 0.f);
                const float p2 = fmaxf(s[2] - tau[nf], 0.f);
                const float p3 = fmaxf(s[3] - tau[nf], 0.f);
                const unsigned h0 = cvtpk(p0, p1);
                const unsigned h1 = cvtpk(p2, p3);
                const unsigned l0 = cvtpk(p0 - __uint_as_float(h0 << 16),
                                          p1 - __uint_as_float(h0 & 0xFFFF0000u));
                const unsigned l1 = cvtpk(p2 - __uint_as_float(h1 << 16),
                                          p3 - __uint_as_float(h1 & 0xFFFF0000u));
                *(u64*)&Pst[w][0][c][m01 * 16 + g * 4] = (u64)h0 | ((u64)h1 << 32);
                *(u64*)&Pst[w][1][c][m01 * 16 + g * 4] = (u64)l0 | ((u64)l1 << 32);
            }
            const bf16x8 Bhi = *(const bf16x8*)&Pst[w][0][c][g * 8];
            const bf16x8 Blo = *(const bf16x8*)&Pst[w][1][c][g * 8];
#pragma unroll
            for (int mo = 0; mo < 4; ++mo) {
                f32x4 t = Oacc[mo][nf];
                t = __builtin_amdgcn_mfma_f32_16x16x32_bf16(vh[mo], Bhi, t, 0, 0, 0);
                t = __builtin_amdgcn_mfma_f32_16x16x32_bf16(vh[mo], Blo, t, 0, 0, 0);
                t = __builtin_amdgcn_mfma_f32_16x16x32_bf16(vl[mo], Bhi, t, 0, 0, 0);
                Oacc[mo][nf] = t;
            }
        }
    }

    // cross-wave reduce (two nf phases)
    const int b_ = bh >> 3, h_ = bh & 7;
#pragma unroll
    for (int nf = 0; nf < 2; ++nf) {
        if (nf) __syncthreads();
#pragma unroll
        for (int mo = 0; mo < 4; ++mo)
#pragma unroll
            for (int r = 0; r < 4; ++r)
                Opart[w][c][mo * 16 + 4 * g + r] = Oacc[mo][nf][r];
        __syncthreads();
#pragma unroll
        for (int p = 0; p < 2; ++p) {
            const int idx2 = p * 512 + tid;
            const int d = idx2 & 63;
            const int i = idx2 >> 6;
            float sv = 0.f;
#pragma unroll
            for (int ww = 0; ww < 8; ++ww) sv += Opart[ww][i][d];
            const int irow = q0 + nf * 16 + i;
            const size_t oa = (size_t)(irow * BATCH + b_) * EMB + h_ * 64 + d;
            const u16 hv = f2bf(sv);
            aoh[oa] = hv;
            aol[oa] = f2bf(sv - bf2f(hv));
        }
    }
}

// =====================================================================
// GEMM2 (MFMA, split): ao @ opw^T + opb -> d_out f32. grid (32,8) blk 256.
// LDS-staged coalesced epilogue.
// =====================================================================
__global__ __launch_bounds__(256, 4) void gemm_out_mfma(
    const u16* __restrict__ aoh, const u16* __restrict__ aol,
    const u16* __restrict__ owh, const u16* __restrict__ owl,
    const float* __restrict__ opb, float* __restrict__ out)
{
    __shared__ float Et[128 * 68];

    const int t0 = blockIdx.x * 128;
    const int o0 = blockIdx.y * 64;

    const int tid = threadIdx.x;
    const int w   = tid >> 6;
    const int l   = tid & 63;
    const int c   = l & 15;
    const int g   = l >> 4;

    f32x4 acc[2][4];
#pragma unroll
    for (int mf = 0; mf < 2; ++mf)
#pragma unroll
        for (int nf = 0; nf < 4; ++nf) acc[mf][nf] = (f32x4){0.f, 0.f, 0.f, 0.f};

    const int arow0 = t0 + w * 32 + c;
#pragma unroll
    for (int ks = 0; ks < 16; ++ks) {
        const int k0 = ks * 32 + g * 8;
        bf16x8 ah[2], al[2], bh[4], bl[4];
#pragma unroll
        for (int mf = 0; mf < 2; ++mf) {
            const size_t r = (size_t)(arow0 + mf * 16) * EMB + k0;
            ah[mf] = *(const bf16x8*)&aoh[r];
            al[mf] = *(const bf16x8*)&aol[r];
        }
#pragma unroll
        for (int nf = 0; nf < 4; ++nf) {
            const size_t r = (size_t)(o0 + nf * 16 + c) * EMB + k0;
            bh[nf] = *(const bf16x8*)&owh[r];
            bl[nf] = *(const bf16x8*)&owl[r];
        }
#pragma unroll
        for (int mf = 0; mf < 2; ++mf)
#pragma unroll
            for (int nf = 0; nf < 4; ++nf) {
                f32x4 t = acc[mf][nf];
                t = __builtin_amdgcn_mfma_f32_16x16x32_bf16(ah[mf], bh[nf], t, 0, 0, 0);
                t = __builtin_amdgcn_mfma_f32_16x16x32_bf16(al[mf], bh[nf], t, 0, 0, 0);
                t = __builtin_amdgcn_mfma_f32_16x16x32_bf16(ah[mf], bl[nf], t, 0, 0, 0);
                acc[mf][nf] = t;
            }
    }

    // stage (+bias) to LDS
#pragma unroll
    for (int mf = 0; mf < 2; ++mf)
#pragma unroll
        for (int j = 0; j < 4; ++j) {
            const int tl = w * 32 + mf * 16 + g * 4 + j;
#pragma unroll
            for (int nf = 0; nf < 4; ++nf)
                Et[tl * 68 + nf * 16 + c] = acc[mf][nf][j] + opb[o0 + nf * 16 + c];
        }
    __syncthreads();

    // coalesced stores: 128 rows x 64 f32; 16 threads per row
    const int part = tid & 15;
#pragma unroll
    for (int p = 0; p < 8; ++p) {
        const int row = p * 16 + (tid >> 4);
        const float4 v = *(const float4*)&Et[row * 68 + part * 4];
        *(float4*)&out[(size_t)(t0 + row) * EMB + o0 + part * 4] = v;
    }
}

// =====================================================================
extern "C" void kernel_launch(void* const* d_in, const int* in_sizes, int n_in,
                              void* d_out, int out_size, void* d_ws, size_t ws_size,
                              hipStream_t stream)
{
    const float* query = (const float*)d_in[0];
    const float* key_  = (const float*)d_in[1];
    const float* value = (const float*)d_in[2];
    const float* ipw   = (const float*)d_in[3];
    const float* ipb   = (const float*)d_in[4];
    const float* opw   = (const float*)d_in[5];
    const float* opb   = (const float*)d_in[6];
    // d_in[7] = update_steps_max (0)

    char* ws = (char*)d_ws;
    const size_t MB = 1024 * 1024;
    u16* qhi = (u16*)(ws + 0 * MB);    // 4 MB each
    u16* qlo = (u16*)(ws + 4 * MB);
    u16* khi = (u16*)(ws + 8 * MB);
    u16* klo = (u16*)(ws + 12 * MB);
    u16* vth = (u16*)(ws + 16 * MB);   // transposed V [bh][64][2048]
    u16* vtl = (u16*)(ws + 20 * MB);
    u16* aoh = (u16*)(ws + 24 * MB);
    u16* aol = (u16*)(ws + 28 * MB);
    u16* iwh = (u16*)(ws + 32 * MB);
    u16* iwl = (u16*)(ws + 34 * MB);
    u16* owh = (u16*)(ws + 36 * MB);
    u16* owl = (u16*)(ws + 37 * MB);
    float* out = (float*)d_out;
    (void)ws_size; (void)in_sizes; (void)n_in; (void)out_size;

    convert_w<<<1024, 256, 0, stream>>>(ipw, opw, iwh, iwl, owh, owl);
    gemm_qkv_ln_mfma<<<dim3(32, 8, 3), 256, 0, stream>>>(
        query, key_, value, iwh, iwl, ipb, qhi, qlo, khi, klo, vth, vtl);
    attn_sparsemax_mfma<<<1024, 512, 0, stream>>>(
        qhi, qlo, khi, klo, vth, vtl, aoh, aol);
    gemm_out_mfma<<<dim3(32, 8), 256, 0, stream>>>(
        aoh, aol, owh, owl, opb, out);
}